// Round 19
// baseline (298.726 us; speedup 1.0000x reference)
//
#include <hip/hip_runtime.h>
#include <math.h>

#define N_NODES 50000
#define IN_DIM  256
#define LATENT  128
#define FINALD  64
#define NGRAPH  2
#define NEDGE   1000000
#define BATCHSZ 16384

#define VN4     (4 * N_NODES)          // unified virtual dst ids: side*2N + g*N + dst
#define NBU     ((VN4 + 255) >> 8)     // 782 buckets of 256 vds
#define E4      (4 * NEDGE)
#define NPB     256                    // partition blocks
#define PCH     ((E4 + NPB - 1) / NPB) // 15625 edges per partition block
#define BCAP    8192                   // bucket_csr LDS cache entries
#define PREPB   768                    // weight-prep blocks

// weights per side: W1[128][256]bf16 W2a[128][128]f16 W2s[128][256]bf16 W3pad[128][128]bf16
#define WSP_SIDE   98304
#define HSTRIDE    (N_NODES * LATENT)        // per-side ushort stride for H2h
#define H1STRIDE8  ((size_t)N_NODES * 128)   // per-side byte stride for fp8 H1

typedef __attribute__((ext_vector_type(8))) short bf16x8;
typedef __attribute__((ext_vector_type(8))) _Float16 f16x8;
typedef __attribute__((ext_vector_type(4))) float f32x4;
typedef __attribute__((ext_vector_type(2))) float f32x2;
typedef __attribute__((ext_vector_type(8))) unsigned short u16x8;
typedef __attribute__((ext_vector_type(2))) unsigned int u32x2;

// exp2 fast path: scores prescaled by log2(e) (leaky is positively homogeneous)
#if __has_builtin(__builtin_amdgcn_exp2f)
#define LOGSCALE 1.44269504f
#define EXPW(x)  __builtin_amdgcn_exp2f(x)
#else
#define LOGSCALE 1.0f
#define EXPW(x)  __expf(x)
#endif

__device__ inline unsigned short f2bf(float x) {
    unsigned int u = __float_as_uint(x);
    u = (u + 0x7fffu + ((u >> 16) & 1u)) >> 16;
    return (unsigned short)u;
}
__device__ inline float bf2f(unsigned short h) {
    return __uint_as_float(((unsigned int)h) << 16);
}
__device__ inline unsigned char f2fp8(float x) {
    int p = __builtin_amdgcn_cvt_pk_fp8_f32(x, x, 0, false);
    return (unsigned char)(p & 0xFF);
}
__device__ inline unsigned short f2f16bits(float x) {
    _Float16 h = (_Float16)x;
    return *(unsigned short*)&h;
}
__device__ inline float f16bits2f(unsigned short h) {
    _Float16 x = *(_Float16*)&h;
    return (float)x;
}

#define BM 128
#define BK 64

__device__ inline int swz(int r, int k) {      // [*][64] tiles
    return r * BK + ((((k >> 3) ^ (r & 7)) << 3) | (k & 7));
}
__device__ inline int swz2(int r, int c) {     // [*][128] tiles
    return r * 128 + ((((c >> 3) ^ (r & 7)) << 3) | (c & 7));
}

__device__ inline void edge_decomp(int i, int& side, int& g, int& idx) {
    if (i < NEDGE)          { side = 0; g = 0; idx = i; }
    else if (i < 2 * NEDGE) { side = 0; g = 1; idx = i - NEDGE; }
    else if (i < 3 * NEDGE) { side = 1; g = 0; idx = i - 2 * NEDGE; }
    else                    { side = 1; g = 1; idx = i - 3 * NEDGE; }
}

// ---------------------------------------------------------------------------
// FAT1: part_count (0..NPB) || prep_weights (NPB..NPB+PREPB)
// ---------------------------------------------------------------------------
__global__ __launch_bounds__(256)
void fat_count_prep(const int* __restrict__ eU, const int* __restrict__ eB,
                    int* __restrict__ pcnt,
                    const float* __restrict__ W1u, const float* __restrict__ Wu2,
                    const float* __restrict__ Wus2, const float* __restrict__ Wu3,
                    const float* __restrict__ W1b, const float* __restrict__ Wb2,
                    const float* __restrict__ Wbs2, const float* __restrict__ Wb3,
                    unsigned short* __restrict__ dst)
{
    __shared__ int h[NBU];
    int tid = threadIdx.x;
    if (blockIdx.x < NPB) {
        for (int i = tid; i < NBU; i += 256) h[i] = 0;
        __syncthreads();
        int start = blockIdx.x * PCH;
        int stop  = min(start + PCH, E4);
        for (int i = start + tid; i < stop; i += 256) {
            int side, g, idx;
            edge_decomp(i, side, g, idx);
            const int* base = side ? eB : eU;
            int d = base[(size_t)(2 * g + 1) * NEDGE + idx];
            int vd = side * (2 * N_NODES) + g * N_NODES + d;
            atomicAdd(&h[vd >> 8], 1);
        }
        __syncthreads();
        for (int i = tid; i < NBU; i += 256)
            pcnt[i * NPB + blockIdx.x] = h[i];
    } else {
        int e = (blockIdx.x - NPB) * 256 + tid;
        if (e >= 2 * WSP_SIDE) return;
        int side = e >= WSP_SIDE;
        int r = e - (side ? WSP_SIDE : 0);
        const float* src; int K, hoff; int w3 = 0, fp16 = 0;
        if (r < 32768)      { src = side ? W1b  : W1u;  K = 256; hoff = 0;     }
        else if (r < 49152) { src = side ? Wb2  : Wu2;  K = 128; hoff = 32768; r -= 32768; fp16 = 1; }
        else if (r < 81920) { src = side ? Wbs2 : Wus2; K = 256; hoff = 49152; r -= 49152; }
        else                { src = side ? Wb3  : Wu3;  K = 128; hoff = 81920; r -= 81920; w3 = 1; }
        int n = (K == 256) ? (r >> 8) : (r >> 7);
        int k = (K == 256) ? (r & 255) : (r & 127);
        float x;
        if (w3) x = (n < 64) ? src[k * 64 + n] : 0.f;
        else    x = src[k * 128 + n];
        unsigned short o;
        if (fp16) o = f2f16bits(x);
        else      o = f2bf(x);
        dst[(size_t)side * WSP_SIDE + hoff + n * K + k] = o;
    }
}

// ---------------------------------------------------------------------------
__global__ __launch_bounds__(1024)
void part_scan(const int* __restrict__ pcnt, int* __restrict__ pbase,
               int* __restrict__ bbase, int* __restrict__ offs)
{
    __shared__ int btot[NBU];
    __shared__ int wsum2[16];
    int tid = threadIdx.x;
    int lane = tid & 63, w = tid >> 6;           // 16 waves
    for (int b = w; b < NBU; b += 16) {
        int4 v = *(const int4*)&pcnt[b * NPB + lane * 4];
        int s = v.x + v.y + v.z + v.w;
        int x = s;
        #pragma unroll
        for (int o = 1; o < 64; o <<= 1) {
            int y = __shfl_up(x, o);
            if (lane >= o) x += y;
        }
        int ex = x - s;
        int* pb = &pbase[b * NPB + lane * 4];
        pb[0] = ex;
        pb[1] = ex + v.x;
        pb[2] = ex + v.x + v.y;
        pb[3] = ex + v.x + v.y + v.z;
        if (lane == 63) btot[b] = x;
    }
    __syncthreads();
    int v = (tid < NBU) ? btot[tid] : 0;
    int x = v;
    #pragma unroll
    for (int o = 1; o < 64; o <<= 1) {
        int y = __shfl_up(x, o);
        if (lane >= o) x += y;
    }
    if (lane == 63) wsum2[w] = x;
    __syncthreads();
    int wb = 0;
    for (int i = 0; i < w; ++i) wb += wsum2[i];
    int ex = wb + x - v;
    if (tid < NBU) bbase[tid] = ex;
    if (tid == NBU - 1) bbase[NBU] = ex + v;
    if (tid == 0) offs[VN4] = E4;
}

// ---------------------------------------------------------------------------
// FAT2: part_fill (0..NPB) || gemm_h1+rowdots (NPB..NPB+782).
// gemm_h1: H1f8 = fp8_e4m3(S @ W1) (bf16 MFMA), fused asf/anb row-dots
// (pre-scaled by LOGSCALE for the exp2 fast path).
// ---------------------------------------------------------------------------
__global__ __launch_bounds__(256)
void fat_fill_gemm1(const int* __restrict__ eU, const int* __restrict__ eB,
                    const int* __restrict__ pbase, const int* __restrict__ bbase,
                    int* __restrict__ ebuf,
                    const float* __restrict__ Su, const float* __restrict__ Sb,
                    const unsigned short* __restrict__ wspb,
                    const float* __restrict__ aself_u, const float* __restrict__ anbv_u,
                    const float* __restrict__ aself_b, const float* __restrict__ anbv_b,
                    unsigned char* __restrict__ H1f8, float* __restrict__ asf,
                    float* __restrict__ anb, int M)
{
    __shared__ unsigned short AhS[BM * BK];
    __shared__ unsigned short BhS[BM * BK];
    __shared__ float dotL[BM][2];
    __shared__ int lbase[NBU];
    __shared__ int lcur[NBU];

    int tid = threadIdx.x;

    if (blockIdx.x < NPB) {
        for (int i = tid; i < NBU; i += 256) {
            lbase[i] = bbase[i] + pbase[i * NPB + blockIdx.x];
            lcur[i] = 0;
        }
        __syncthreads();
        int start = blockIdx.x * PCH;
        int stop  = min(start + PCH, E4);
        for (int i = start + tid; i < stop; i += 256) {
            int side, g, idx;
            edge_decomp(i, side, g, idx);
            const int* base = side ? eB : eU;
            int src = base[(size_t)(2 * g) * NEDGE + idx];
            int d = base[(size_t)(2 * g + 1) * NEDGE + idx];
            int vd = side * (2 * N_NODES) + g * N_NODES + d;
            int b = vd >> 8;
            int p = lbase[b] + atomicAdd(&lcur[b], 1);
            ebuf[p] = ((vd & 255) << 16) | src;
        }
        return;
    }

    // ----- gemm_h1 -----
    int t = blockIdx.x - NPB;             // 0..781
    const int side = t / 391;
    const int rowBase = (t % 391) * BM;
    const float* Ap = side ? Sb : Su;
    const unsigned short* Bp = wspb + (size_t)side * WSP_SIDE;   // W1 slot (bf16)
    const float* avs = side ? aself_b : aself_u;
    const float* avn = side ? anbv_b : anbv_u;
    unsigned char* Cout = H1f8 + (size_t)side * H1STRIDE8;

    const int wave = tid >> 6, lane = tid & 63;
    const int wr = wave >> 1, wc = wave & 1;
    const int sl = lane & 15, lg = lane >> 4;
    const int K = IN_DIM;

    if (tid < BM) { dotL[tid][0] = 0.f; dotL[tid][1] = 0.f; }

    f32x4 acc[4][4] = {};

    for (int k0 = 0; k0 < K; k0 += BK) {
        __syncthreads();
        #pragma unroll
        for (int p = 0; p < 4; ++p) {
            int q = p * 256 + tid;
            int row = q >> 3;
            int kq = (q & 7) << 3;
            int grow = rowBase + row;
            u16x8 hv = {0, 0, 0, 0, 0, 0, 0, 0};
            if (grow < M) {
                const float* a = Ap + (size_t)grow * K + k0 + kq;
                float4 v0 = *(const float4*)a;
                float4 v1 = *(const float4*)(a + 4);
                hv[0] = f2bf(v0.x); hv[1] = f2bf(v0.y); hv[2] = f2bf(v0.z); hv[3] = f2bf(v0.w);
                hv[4] = f2bf(v1.x); hv[5] = f2bf(v1.y); hv[6] = f2bf(v1.z); hv[7] = f2bf(v1.w);
            }
            *(u16x8*)&AhS[swz(row, kq)] = hv;
        }
        #pragma unroll
        for (int p = 0; p < 4; ++p) {
            int q = p * 256 + tid;
            int n = q >> 3;
            int kq = (q & 7) << 3;
            u16x8 hv = *(const u16x8*)(Bp + (size_t)n * K + k0 + kq);
            *(u16x8*)&BhS[swz(n, kq)] = hv;
        }
        __syncthreads();
        #pragma unroll
        for (int ks = 0; ks < 2; ++ks) {
            int kof = ks * 32 + lg * 8;
            bf16x8 af[4], bf[4];
            #pragma unroll
            for (int f = 0; f < 4; ++f) {
                af[f] = *(const bf16x8*)&AhS[swz(wr * 64 + f * 16 + sl, kof)];
                bf[f] = *(const bf16x8*)&BhS[swz(wc * 64 + f * 16 + sl, kof)];
            }
            #pragma unroll
            for (int fm = 0; fm < 4; ++fm)
                #pragma unroll
                for (int fn = 0; fn < 4; ++fn)
                    acc[fm][fn] = __builtin_amdgcn_mfma_f32_16x16x32_bf16(af[fm], bf[fn], acc[fm][fn], 0, 0, 0);
        }
    }

    // C write (fp8 e4m3, byte stores)
    #pragma unroll
    for (int fm = 0; fm < 4; ++fm)
        #pragma unroll
        for (int r = 0; r < 4; ++r) {
            int row = rowBase + wr * 64 + fm * 16 + lg * 4 + r;
            if (row >= M) continue;
            #pragma unroll
            for (int fn = 0; fn < 4; ++fn) {
                int col = wc * 64 + fn * 16 + sl;
                Cout[(size_t)row * 128 + col] = f2fp8(acc[fm][fn][r]);
            }
        }

    // fused rowdots (full-precision acc)
    float as_[4], an_[4];
    #pragma unroll
    for (int fn = 0; fn < 4; ++fn) {
        int col = wc * 64 + fn * 16 + sl;
        as_[fn] = avs[col];
        an_[fn] = avn[col];
    }
    #pragma unroll
    for (int fm = 0; fm < 4; ++fm)
        #pragma unroll
        for (int r = 0; r < 4; ++r) {
            float p1 = 0.f, p2 = 0.f;
            #pragma unroll
            for (int fn = 0; fn < 4; ++fn) {
                float v = acc[fm][fn][r];
                p1 += v * as_[fn];
                p2 += v * an_[fn];
            }
            #pragma unroll
            for (int o = 1; o <= 8; o <<= 1) {
                p1 += __shfl_xor(p1, o);
                p2 += __shfl_xor(p2, o);
            }
            if (sl == 0) {
                int row_l = wr * 64 + fm * 16 + lg * 4 + r;
                atomicAdd(&dotL[row_l][0], p1);
                atomicAdd(&dotL[row_l][1], p2);
            }
        }
    __syncthreads();
    if (tid < BM) {
        int row = rowBase + tid;
        if (row < M) {
            asf[side * M + row] = dotL[tid][0] * LOGSCALE;
            anb[side * M + row] = dotL[tid][1] * LOGSCALE;
        }
    }
}

// ---------------------------------------------------------------------------
// bucket_csr: sort edges by dst within bucket AND precompute the per-edge
// unnormalized softmax weight w = exp2(leaky(asf+anb)) (f16), packed as
// csrw[e] = (f16bits(w) << 16) | src. Removes score work from the gather.
// ---------------------------------------------------------------------------
__global__ __launch_bounds__(256)
void bucket_csr(const int* __restrict__ ebuf, const int* __restrict__ bbase,
                int* __restrict__ offs, unsigned int* __restrict__ csrw,
                const float* __restrict__ asf, const float* __restrict__ anb)
{
    __shared__ int lds_e[BCAP];
    __shared__ int cnt[256];
    __shared__ int excl[256];
    __shared__ int cur[256];
    __shared__ int wsum[4];
    int tid = threadIdx.x;
    int b = blockIdx.x;
    int lo = bbase[b], hi = bbase[b + 1];
    int sz = hi - lo;

    cnt[tid] = 0; cur[tid] = 0;
    __syncthreads();
    for (int i = tid; i < sz; i += 256) {
        int v = ebuf[lo + i];
        if (i < BCAP) lds_e[i] = v;
        atomicAdd(&cnt[v >> 16], 1);
    }
    __syncthreads();

    int lane = tid & 63, w = tid >> 6;
    int v = cnt[tid];
    int x = v;
    #pragma unroll
    for (int o = 1; o < 64; o <<= 1) {
        int y = __shfl_up(x, o);
        if (lane >= o) x += y;
    }
    if (lane == 63) wsum[w] = x;
    __syncthreads();
    int wb = 0;
    for (int i = 0; i < w; ++i) wb += wsum[i];
    int ex = wb + x - v;
    excl[tid] = ex;
    int vd0 = b * 256 + tid;
    if (vd0 < VN4) offs[vd0] = lo + ex;
    __syncthreads();

    for (int i = tid; i < sz; i += 256) {
        int e = (i < BCAP) ? lds_e[i] : ebuf[lo + i];
        int dl = e >> 16;
        int src = e & 0xFFFF;
        int p = excl[dl] + atomicAdd(&cur[dl], 1);
        int vd = b * 256 + dl;
        int side = vd >= 2 * N_NODES;
        int rem = vd - side * 2 * N_NODES;
        int g = rem >= N_NODES;
        int dd = rem - g * N_NODES;
        float sc = asf[side * N_NODES + dd] + anb[side * N_NODES + src];
        sc = fmaxf(sc, 0.2f * sc);
        float wv = EXPW(sc);
        csrw[lo + p] = ((unsigned int)f2f16bits(wv) << 16) | (unsigned int)src;
    }
}

// ---------------------------------------------------------------------------
// GAT aggregation: fp8 H1 gather with precomputed f16 edge weights.
// Single load per edge; deferred normalization; 16-lane groups, 2-deep.
// ---------------------------------------------------------------------------
__global__ __launch_bounds__(256)
void gat_gather(const unsigned char* __restrict__ H1f8,
                const int* __restrict__ offs, const unsigned int* __restrict__ csrw,
                const float* __restrict__ omu, const float* __restrict__ omb,
                unsigned short* __restrict__ H2h, int n)
{
    int side = blockIdx.y;
    int lane = threadIdx.x & 63, wid = threadIdx.x >> 6;
    int d = blockIdx.x * 4 + wid;
    if (d >= n) return;
    const unsigned char* Hbase = H1f8 + (size_t)side * H1STRIDE8;
    const int* offside = offs + side * 2 * N_NODES;
    const float* om_p = side ? omb : omu;
    int sub = lane >> 4, sl = lane & 15;
    const unsigned char* Hp = Hbase + (sl << 3);
    float fin[8] = {};

    #pragma unroll
    for (int g = 0; g < NGRAPH; ++g) {
        int beg = offside[g * n + d], end = offside[g * n + d + 1];
        float om = om_p[g];
        float un[8] = {};
        float ss = 0.f;

        int e = beg + sub;
        for (; e + 4 < end; e += 8) {
            unsigned int v0 = csrw[e], v1 = csrw[e + 4];
            int s0 = v0 & 0xFFFF, s1 = v1 & 0xFFFF;
            u32x2 b0 = *(const u32x2*)(Hp + (size_t)s0 * 128);
            u32x2 b1 = *(const u32x2*)(Hp + (size_t)s1 * 128);
            float w0 = f16bits2f((unsigned short)(v0 >> 16));
            float w1 = f16bits2f((unsigned short)(v1 >> 16));
            ss += w0 + w1;
            {
                f32x2 q0 = __builtin_amdgcn_cvt_pk_f32_fp8(b0[0], false);
                f32x2 q1 = __builtin_amdgcn_cvt_pk_f32_fp8(b0[0], true);
                f32x2 q2 = __builtin_amdgcn_cvt_pk_f32_fp8(b0[1], false);
                f32x2 q3 = __builtin_amdgcn_cvt_pk_f32_fp8(b0[1], true);
                un[0] += w0 * q0[0]; un[1] += w0 * q0[1];
                un[2] += w0 * q1[0]; un[3] += w0 * q1[1];
                un[4] += w0 * q2[0]; un[5] += w0 * q2[1];
                un[6] += w0 * q3[0]; un[7] += w0 * q3[1];
            }
            {
                f32x2 q0 = __builtin_amdgcn_cvt_pk_f32_fp8(b1[0], false);
                f32x2 q1 = __builtin_amdgcn_cvt_pk_f32_fp8(b1[0], true);
                f32x2 q2 = __builtin_amdgcn_cvt_pk_f32_fp8(b1[1], false);
                f32x2 q3 = __builtin_amdgcn_cvt_pk_f32_fp8(b1[1], true);
                un[0] += w1 * q0[0]; un[1] += w1 * q0[1];
                un[2] += w1 * q1[0]; un[3] += w1 * q1[1];
                un[4] += w1 * q2[0]; un[5] += w1 * q2[1];
                un[6] += w1 * q3[0]; un[7] += w1 * q3[1];
            }
        }
        if (e < end) {
            unsigned int v0 = csrw[e];
            int s0 = v0 & 0xFFFF;
            u32x2 b0 = *(const u32x2*)(Hp + (size_t)s0 * 128);
            float w0 = f16bits2f((unsigned short)(v0 >> 16));
            ss += w0;
            f32x2 q0 = __builtin_amdgcn_cvt_pk_f32_fp8(b0[0], false);
            f32x2 q1 = __builtin_amdgcn_cvt_pk_f32_fp8(b0[0], true);
            f32x2 q2 = __builtin_amdgcn_cvt_pk_f32_fp8(b0[1], false);
            f32x2 q3 = __builtin_amdgcn_cvt_pk_f32_fp8(b0[1], true);
            un[0] += w0 * q0[0]; un[1] += w0 * q0[1];
            un[2] += w0 * q1[0]; un[3] += w0 * q1[1];
            un[4] += w0 * q2[0]; un[5] += w0 * q2[1];
            un[6] += w0 * q3[0]; un[7] += w0 * q3[1];
        }

        // cross-group sum of exp (groups hold disjoint edge subsets)
        ss += __shfl_xor(ss, 32);
        ss += __shfl_xor(ss, 16);
        float wsc = om / (ss + 1e-16f);
        #pragma unroll
        for (int j = 0; j < 8; ++j) fin[j] += wsc * un[j];
    }

    #pragma unroll
    for (int j = 0; j < 8; ++j) {
        fin[j] += __shfl_xor(fin[j], 32);
        fin[j] += __shfl_xor(fin[j], 16);
    }
    if (sub == 0) {
        f16x8 o;
        #pragma unroll
        for (int j = 0; j < 8; ++j) o[j] = (_Float16)fin[j];
        *(f16x8*)(H2h + (size_t)side * HSTRIDE + (size_t)d * LATENT + sl * 8) = o;
    }
}

// ---------------------------------------------------------------------------
// Fused GEMM2+GEMM3: H3 = elu(H2@W2a + S@W2s + b2) in LDS (bf16), then
// OUT = elu(H3@W3) + H4. Pass0 f16 MFMA (H2/W2a f16), pass1 bf16.
// ---------------------------------------------------------------------------
__global__ __launch_bounds__(256)
void gemm_fused23(const unsigned short* __restrict__ H2h,
                  const float* __restrict__ Su, const float* __restrict__ Sb,
                  const unsigned short* __restrict__ wspb,
                  const float* __restrict__ b2u, const float* __restrict__ b2b,
                  const float* __restrict__ H4u, const float* __restrict__ H4b,
                  float* __restrict__ Uo, float* __restrict__ Bo, int M)
{
    __shared__ unsigned short sm[BM * BK * 2];   // AhS/BhS; H3S overlays (32KB)
    __shared__ unsigned short W3S[64 * 128];     // 16KB
    unsigned short* AhS = sm;
    unsigned short* BhS = sm + BM * BK;

    const int side = blockIdx.z;
    const unsigned short* Bside = wspb + (size_t)side * WSP_SIDE;
    const float* bias = side ? b2b : b2u;
    const float* H4 = side ? H4b : H4u;
    float* Cout = side ? Bo : Uo;

    const int tid = threadIdx.x;
    const int rowBase = blockIdx.x * BM;
    const int wave = tid >> 6, lane = tid & 63;
    const int wr = wave >> 1, wc = wave & 1;
    const int sl = lane & 15, lg = lane >> 4;

    // preload W3 [64][128] bf16 k-major (swizzled)
    {
        const unsigned short* w3 = Bside + 81920;
        #pragma unroll
        for (int p = 0; p < 4; ++p) {
            int i = p * 256 + tid;
            int n = i >> 4;
            int kq = (i & 15) << 3;
            u16x8 v = *(const u16x8*)(w3 + (size_t)n * 128 + kq);
            *(u16x8*)&W3S[swz2(n, kq)] = v;
        }
    }

    f32x4 acc[4][4] = {};

    // ---- pass 0: A = H2 (f16), B = W2a (f16), K = 128
    {
        const unsigned short* Ap = H2h + (size_t)side * HSTRIDE;
        const unsigned short* Bp = Bside + 32768;
        const int K = LATENT;
        for (int k0 = 0; k0 < K; k0 += BK) {
            __syncthreads();
            #pragma unroll
            for (int p = 0; p < 4; ++p) {
                int q = p * 256 + tid;
                int row = q >> 3;
                int kq = (q & 7) << 3;
                int grow = rowBase + row;
                u16x8 hv = {0, 0, 0, 0, 0, 0, 0, 0};
                if (grow < M)
                    hv = *(const u16x8*)(Ap + (size_t)grow * K + k0 + kq);
                *(u16x8*)&AhS[swz(row, kq)] = hv;
            }
            #pragma unroll
            for (int p = 0; p < 4; ++p) {
                int q = p * 256 + tid;
                int n = q >> 3;
                int kq = (q & 7) << 3;
                u16x8 hv = *(const u16x8*)(Bp + (size_t)n * K + k0 + kq);
                *(u16x8*)&BhS[swz(n, kq)] = hv;
            }
            __syncthreads();
            #pragma unroll
            for (int ks = 0; ks < 2; ++ks) {
                int kof = ks * 32 + lg * 8;
                f16x8 af[4], bf[4];
                #pragma unroll
                for (int f = 0; f < 4; ++f) {
                    af[f] = *(const f16x8*)&AhS[swz(wr * 64 + f * 16 + sl, kof)];
                    bf[f] = *(const f16x8*)&BhS[swz(wc * 64 + f * 16 + sl, kof)];
                }
                #pragma unroll
                for (int fm = 0; fm < 4; ++fm)
                    #pragma unroll
                    for (int fn = 0; fn < 4; ++fn)
                        acc[fm][fn] = __builtin_amdgcn_mfma_f32_16x16x32_f16(af[fm], bf[fn], acc[fm][fn], 0, 0, 0);
            }
        }
    }

    // ---- pass 1: A = S (f32->bf16), B = W2s (bf16), K = 256
    {
        const float* Ap = side ? Sb : Su;
        const unsigned short* Bp = Bside + 49152;
        const int K = IN_DIM;
        for (int k0 = 0; k0 < K; k0 += BK) {
            __syncthreads();
            #pragma unroll
            for (int p = 0; p < 4; ++p) {
                int q = p * 256 + tid;
                int row = q >> 3;
                int kq = (q & 7) << 3;
                int grow = rowBase + row;
                u16x8 hv = {0, 0, 0, 0, 0, 0, 0, 0};
                if (grow < M) {
                    const float* a = Ap + (size_t)grow * K + k0 + kq;
                    float4 v0 = *(const float4*)a;
                    float4 v1 = *(const float4*)(a + 4);
                    hv[0] = f2bf(v0.x); hv[1] = f2bf(v0.y); hv[2] = f2bf(v0.z); hv[3] = f2bf(v0.w);
                    hv[4] = f2bf(v1.x); hv[5] = f2bf(v1.y); hv[6] = f2bf(v1.z); hv[7] = f2bf(v1.w);
                }
                *(u16x8*)&AhS[swz(row, kq)] = hv;
            }
            #pragma unroll
            for (int p = 0; p < 4; ++p) {
                int q = p * 256 + tid;
                int n = q >> 3;
                int kq = (q & 7) << 3;
                u16x8 hv = *(const u16x8*)(Bp + (size_t)n * K + k0 + kq);
                *(u16x8*)&BhS[swz(n, kq)] = hv;
            }
            __syncthreads();
            #pragma unroll
            for (int ks = 0; ks < 2; ++ks) {
                int kof = ks * 32 + lg * 8;
                bf16x8 af[4], bf[4];
                #pragma unroll
                for (int f = 0; f < 4; ++f) {
                    af[f] = *(const bf16x8*)&AhS[swz(wr * 64 + f * 16 + sl, kof)];
                    bf[f] = *(const bf16x8*)&BhS[swz(wc * 64 + f * 16 + sl, kof)];
                }
                #pragma unroll
                for (int fm = 0; fm < 4; ++fm)
                    #pragma unroll
                    for (int fn = 0; fn < 4; ++fn)
                        acc[fm][fn] = __builtin_amdgcn_mfma_f32_16x16x32_bf16(af[fm], bf[fn], acc[fm][fn], 0, 0, 0);
            }
        }
    }

    __syncthreads();   // main-loop LDS reads done; reuse sm as H3S
    unsigned short* H3S = sm;   // [128][128] bf16, swz2

    // epilogue 1: H3 = elu(acc + b2) -> LDS
    #pragma unroll
    for (int fm = 0; fm < 4; ++fm)
        #pragma unroll
        for (int r = 0; r < 4; ++r) {
            int row_l = wr * 64 + fm * 16 + lg * 4 + r;
            #pragma unroll
            for (int fn = 0; fn < 4; ++fn) {
                int col = wc * 64 + fn * 16 + sl;
                float v = acc[fm][fn][r] + bias[col];
                v = v > 0.f ? v : (__expf(v) - 1.f);
                H3S[swz2(row_l, col)] = f2bf(v);
            }
        }
    __syncthreads();

    // matmul2: OUT[128][64] = H3 @ W3, K=128 (bf16)
    f32x4 acc2[4][2] = {};
    #pragma unroll
    for (int ks = 0; ks < 4; ++ks) {
        int kof = ks * 32 + lg * 8;
        bf16x8 a2[4], b2f[2];
        #pragma unroll
        for (int f = 0; f < 4; ++f)
            a2[f] = *(const bf16x8*)&H3S[swz2(wr * 64 + f * 16 + sl, kof)];
        #pragma unroll
        for (int f = 0; f < 2; ++f)
            b2f[f] = *(const bf16x8*)&W3S[swz2(wc * 32 + f * 16 + sl, kof)];
        #pragma unroll
        for (int fm = 0; fm < 4; ++fm)
            #pragma unroll
            for (int fn = 0; fn < 2; ++fn)
                acc2[fm][fn] = __builtin_amdgcn_mfma_f32_16x16x32_bf16(a2[fm], b2f[fn], acc2[fm][fn], 0, 0, 0);
    }

    // epilogue 2: OUT = elu(acc2) + H4
    #pragma unroll
    for (int fm = 0; fm < 4; ++fm)
        #pragma unroll
        for (int r = 0; r < 4; ++r) {
            int row = rowBase + wr * 64 + fm * 16 + lg * 4 + r;
            if (row >= M) continue;
            #pragma unroll
            for (int fn = 0; fn < 2; ++fn) {
                int col = wc * 32 + fn * 16 + sl;
                float v = acc2[fm][fn][r];
                v = v > 0.f ? v : (__expf(v) - 1.f);
                v += H4[(size_t)row * FINALD + col];
                Cout[(size_t)row * FINALD + col] = v;
            }
        }
}

// ---------------------------------------------------------------------------
__global__ __launch_bounds__(256)
void predict(const int* __restrict__ uid, const int* __restrict__ iid,
             const float* __restrict__ U, const float* __restrict__ B,
             const float* __restrict__ bu, const float* __restrict__ bb,
             const float* __restrict__ bx, float* __restrict__ out, int batch)
{
    int lane = threadIdx.x & 63, wid = threadIdx.x >> 6;
    int b = blockIdx.x * 4 + wid;
    if (b >= batch) return;
    int u = uid[b], it = iid[b];
    float p = U[(size_t)u * FINALD + lane] * B[(size_t)it * FINALD + lane];
    #pragma unroll
    for (int o = 32; o; o >>= 1) p += __shfl_xor(p, o);
    if (lane == 0) {
        float raw = p + bu[u] + bb[it] + bx[0];
        out[b] = 4.f * (1.f / (1.f + __expf(-raw))) + 1.f;
    }
}

// ---------------------------------------------------------------------------
extern "C" void kernel_launch(void* const* d_in, const int* in_sizes, int n_in,
                              void* d_out, int out_size, void* d_ws, size_t ws_size,
                              hipStream_t stream)
{
    const int N = N_NODES;

    float* ws = (float*)d_ws;
    unsigned char* H1f8 = (unsigned char*)ws;            // 2 sides fp8 (12.8 MB)
    unsigned short* H2h = (unsigned short*)(ws + 6400000);
    float* U_all = ws + 12800000;
    float* B_all = ws + 16000000;
    float* asf   = ws + 19200000;                        // [2][N]
    float* anb   = asf + 2 * N;                          // [2][N]
    int*   offs  = (int*)(anb + 2 * N);                  // VN4+1
    int*   bbase = offs + VN4 + 1;                       // NBU+1
    unsigned int* csrw = (unsigned int*)(bbase + NBU + 1);     // E4 uints (16MB)
    unsigned short* wsp = (unsigned short*)(csrw + E4);
    int*   ebuf  = (int*)H2h;                            // E4 ints (dead before gather)
    int*   pcnt  = (int*)U_all;                          // NBU*NPB
    int*   pbase = pcnt + NBU * NPB;                     // NBU*NPB

    const int* eU = (const int*)d_in[4];
    const int* eB = (const int*)d_in[5];
    const float* Su = (const float*)d_in[2];
    const float* Sb = (const float*)d_in[3];

    // FAT1: edge histogram || weight prep
    fat_count_prep<<<NPB + PREPB, 256, 0, stream>>>(
        eU, eB, pcnt,
        (const float*)d_in[6],  (const float*)d_in[14], (const float*)d_in[15], (const float*)d_in[20],
        (const float*)d_in[10], (const float*)d_in[17], (const float*)d_in[18], (const float*)d_in[21],
        wsp);

    part_scan<<<1, 1024, 0, stream>>>(pcnt, pbase, bbase, offs);

    // FAT2: edge partition fill || H1 GEMM + rowdots
    fat_fill_gemm1<<<NPB + 782, 256, 0, stream>>>(
        eU, eB, pbase, bbase, ebuf,
        Su, Sb, wsp,
        (const float*)d_in[7], (const float*)d_in[8],
        (const float*)d_in[11], (const float*)d_in[12],
        H1f8, asf, anb, N);

    // sort + per-edge weight precompute
    bucket_csr<<<NBU, 256, 0, stream>>>(ebuf, bbase, offs, csrw, asf, anb);

    gat_gather<<<dim3(N / 4, 2), 256, 0, stream>>>(
        H1f8, offs, csrw,
        (const float*)d_in[9], (const float*)d_in[13], H2h, N);

    gemm_fused23<<<dim3(391, 1, 2), 256, 0, stream>>>(
        H2h, Su, Sb, wsp,
        (const float*)d_in[16], (const float*)d_in[19],
        (const float*)d_in[22], (const float*)d_in[23],
        U_all, B_all, N);

    predict<<<BATCHSZ / 4, 256, 0, stream>>>(
        (const int*)d_in[0], (const int*)d_in[1], U_all, B_all,
        (const float*)d_in[24], (const float*)d_in[25], (const float*)d_in[26],
        (float*)d_out, BATCHSZ);
}

// Round 20
// 259.348 us; speedup vs baseline: 1.1518x; 1.1518x over previous
//
#include <hip/hip_runtime.h>
#include <math.h>

#define N_NODES 50000
#define IN_DIM  256
#define LATENT  128
#define FINALD  64
#define NGRAPH  2
#define NEDGE   1000000
#define BATCHSZ 16384

#define VN4     (4 * N_NODES)          // unified virtual dst ids: side*2N + g*N + dst
#define NBU     ((VN4 + 255) >> 8)     // 782 buckets of 256 vds
#define E4      (4 * NEDGE)
#define NPB     256                    // partition blocks
#define PCH     ((E4 + NPB - 1) / NPB) // 15625 edges per partition block
#define BCAP    8192                   // bucket_csr LDS cache entries
#define PREPB   768                    // weight-prep blocks

// weights per side: W1[128][256]bf16 W2a[128][128]f16 W2s[128][256]bf16 W3pad[128][128]bf16
#define WSP_SIDE   98304
#define HSTRIDE    (N_NODES * LATENT)        // per-side ushort stride for H2h
#define H1STRIDE8  ((size_t)N_NODES * 128)   // per-side byte stride for fp8 H1

typedef __attribute__((ext_vector_type(8))) short bf16x8;
typedef __attribute__((ext_vector_type(8))) _Float16 f16x8;
typedef __attribute__((ext_vector_type(2))) _Float16 f16x2;
typedef __attribute__((ext_vector_type(4))) float f32x4;
typedef __attribute__((ext_vector_type(2))) float f32x2;
typedef __attribute__((ext_vector_type(8))) unsigned short u16x8;
typedef __attribute__((ext_vector_type(2))) unsigned int u32x2;

// exp2 fast path: scores prescaled by log2(e) (leaky is positively homogeneous)
#if __has_builtin(__builtin_amdgcn_exp2f)
#define LOGSCALE 1.44269504f
#define EXPW(x)  __builtin_amdgcn_exp2f(x)
#else
#define LOGSCALE 1.0f
#define EXPW(x)  __expf(x)
#endif

__device__ inline unsigned short f2bf(float x) {
    unsigned int u = __float_as_uint(x);
    u = (u + 0x7fffu + ((u >> 16) & 1u)) >> 16;
    return (unsigned short)u;
}
__device__ inline float bf2f(unsigned short h) {
    return __uint_as_float(((unsigned int)h) << 16);
}
__device__ inline unsigned char f2fp8(float x) {
    int p = __builtin_amdgcn_cvt_pk_fp8_f32(x, x, 0, false);
    return (unsigned char)(p & 0xFF);
}
__device__ inline unsigned short f2f16bits(float x) {
    _Float16 h = (_Float16)x;
    return *(unsigned short*)&h;
}

#define BM 128
#define BK 64

__device__ inline int swz(int r, int k) {      // [*][64] tiles
    return r * BK + ((((k >> 3) ^ (r & 7)) << 3) | (k & 7));
}
__device__ inline int swz2(int r, int c) {     // [*][128] tiles
    return r * 128 + ((((c >> 3) ^ (r & 7)) << 3) | (c & 7));
}

__device__ inline void edge_decomp(int i, int& side, int& g, int& idx) {
    if (i < NEDGE)          { side = 0; g = 0; idx = i; }
    else if (i < 2 * NEDGE) { side = 0; g = 1; idx = i - NEDGE; }
    else if (i < 3 * NEDGE) { side = 1; g = 0; idx = i - 2 * NEDGE; }
    else                    { side = 1; g = 1; idx = i - 3 * NEDGE; }
}

// ---------------------------------------------------------------------------
// FAT1: part_count (0..NPB) || prep_weights (NPB..NPB+PREPB)
// ---------------------------------------------------------------------------
__global__ __launch_bounds__(256)
void fat_count_prep(const int* __restrict__ eU, const int* __restrict__ eB,
                    int* __restrict__ pcnt,
                    const float* __restrict__ W1u, const float* __restrict__ Wu2,
                    const float* __restrict__ Wus2, const float* __restrict__ Wu3,
                    const float* __restrict__ W1b, const float* __restrict__ Wb2,
                    const float* __restrict__ Wbs2, const float* __restrict__ Wb3,
                    unsigned short* __restrict__ dst)
{
    __shared__ int h[NBU];
    int tid = threadIdx.x;
    if (blockIdx.x < NPB) {
        for (int i = tid; i < NBU; i += 256) h[i] = 0;
        __syncthreads();
        int start = blockIdx.x * PCH;
        int stop  = min(start + PCH, E4);
        for (int i = start + tid; i < stop; i += 256) {
            int side, g, idx;
            edge_decomp(i, side, g, idx);
            const int* base = side ? eB : eU;
            int d = base[(size_t)(2 * g + 1) * NEDGE + idx];
            int vd = side * (2 * N_NODES) + g * N_NODES + d;
            atomicAdd(&h[vd >> 8], 1);
        }
        __syncthreads();
        for (int i = tid; i < NBU; i += 256)
            pcnt[i * NPB + blockIdx.x] = h[i];
    } else {
        int e = (blockIdx.x - NPB) * 256 + tid;
        if (e >= 2 * WSP_SIDE) return;
        int side = e >= WSP_SIDE;
        int r = e - (side ? WSP_SIDE : 0);
        const float* src; int K, hoff; int w3 = 0, fp16 = 0;
        if (r < 32768)      { src = side ? W1b  : W1u;  K = 256; hoff = 0;     }
        else if (r < 49152) { src = side ? Wb2  : Wu2;  K = 128; hoff = 32768; r -= 32768; fp16 = 1; }
        else if (r < 81920) { src = side ? Wbs2 : Wus2; K = 256; hoff = 49152; r -= 49152; }
        else                { src = side ? Wb3  : Wu3;  K = 128; hoff = 81920; r -= 81920; w3 = 1; }
        int n = (K == 256) ? (r >> 8) : (r >> 7);
        int k = (K == 256) ? (r & 255) : (r & 127);
        float x;
        if (w3) x = (n < 64) ? src[k * 64 + n] : 0.f;
        else    x = src[k * 128 + n];
        unsigned short o;
        if (fp16) o = f2f16bits(x);
        else      o = f2bf(x);
        dst[(size_t)side * WSP_SIDE + hoff + n * K + k] = o;
    }
}

// ---------------------------------------------------------------------------
// Split hierarchical scan: A = per-bucket (782 blocks x 1 wave), B = bucket
// totals (1 block). Replaces the single-block 800KB-read part_scan.
// ---------------------------------------------------------------------------
__global__ __launch_bounds__(64)
void part_scanA(const int* __restrict__ pcnt, int* __restrict__ pbase,
                int* __restrict__ btotg)
{
    int b = blockIdx.x;
    int lane = threadIdx.x;
    int4 v = *(const int4*)&pcnt[b * NPB + lane * 4];
    int s = v.x + v.y + v.z + v.w;
    int x = s;
    #pragma unroll
    for (int o = 1; o < 64; o <<= 1) {
        int y = __shfl_up(x, o);
        if (lane >= o) x += y;
    }
    int ex = x - s;
    int* pb = &pbase[b * NPB + lane * 4];
    pb[0] = ex;
    pb[1] = ex + v.x;
    pb[2] = ex + v.x + v.y;
    pb[3] = ex + v.x + v.y + v.z;
    if (lane == 63) btotg[b] = x;
}

__global__ __launch_bounds__(1024)
void part_scanB(const int* __restrict__ btotg, int* __restrict__ bbase,
                int* __restrict__ offs)
{
    __shared__ int wsum2[16];
    int tid = threadIdx.x;
    int lane = tid & 63, w = tid >> 6;
    int v = (tid < NBU) ? btotg[tid] : 0;
    int x = v;
    #pragma unroll
    for (int o = 1; o < 64; o <<= 1) {
        int y = __shfl_up(x, o);
        if (lane >= o) x += y;
    }
    if (lane == 63) wsum2[w] = x;
    __syncthreads();
    int wb = 0;
    for (int i = 0; i < w; ++i) wb += wsum2[i];
    int ex = wb + x - v;
    if (tid < NBU) bbase[tid] = ex;
    if (tid == NBU - 1) bbase[NBU] = ex + v;
    if (tid == 0) offs[VN4] = E4;
}

// ---------------------------------------------------------------------------
// FAT2: part_fill (0..NPB) || gemm_h1+rowdots (NPB..NPB+782).
// gemm_h1: H1f8 = fp8_e4m3(S @ W1) (bf16 MFMA), fused asf/anb row-dots
// (pre-scaled by LOGSCALE for the exp2 fast path).
// ---------------------------------------------------------------------------
__global__ __launch_bounds__(256)
void fat_fill_gemm1(const int* __restrict__ eU, const int* __restrict__ eB,
                    const int* __restrict__ pbase, const int* __restrict__ bbase,
                    int* __restrict__ ebuf,
                    const float* __restrict__ Su, const float* __restrict__ Sb,
                    const unsigned short* __restrict__ wspb,
                    const float* __restrict__ aself_u, const float* __restrict__ anbv_u,
                    const float* __restrict__ aself_b, const float* __restrict__ anbv_b,
                    unsigned char* __restrict__ H1f8, float* __restrict__ asf,
                    float* __restrict__ anb, int M)
{
    __shared__ unsigned short AhS[BM * BK];
    __shared__ unsigned short BhS[BM * BK];
    __shared__ float dotL[BM][2];
    __shared__ int lbase[NBU];
    __shared__ int lcur[NBU];

    int tid = threadIdx.x;

    if (blockIdx.x < NPB) {
        for (int i = tid; i < NBU; i += 256) {
            lbase[i] = bbase[i] + pbase[i * NPB + blockIdx.x];
            lcur[i] = 0;
        }
        __syncthreads();
        int start = blockIdx.x * PCH;
        int stop  = min(start + PCH, E4);
        for (int i = start + tid; i < stop; i += 256) {
            int side, g, idx;
            edge_decomp(i, side, g, idx);
            const int* base = side ? eB : eU;
            int src = base[(size_t)(2 * g) * NEDGE + idx];
            int d = base[(size_t)(2 * g + 1) * NEDGE + idx];
            int vd = side * (2 * N_NODES) + g * N_NODES + d;
            int b = vd >> 8;
            int p = lbase[b] + atomicAdd(&lcur[b], 1);
            ebuf[p] = ((vd & 255) << 16) | src;
        }
        return;
    }

    // ----- gemm_h1 -----
    int t = blockIdx.x - NPB;             // 0..781
    const int side = t / 391;
    const int rowBase = (t % 391) * BM;
    const float* Ap = side ? Sb : Su;
    const unsigned short* Bp = wspb + (size_t)side * WSP_SIDE;   // W1 slot (bf16)
    const float* avs = side ? aself_b : aself_u;
    const float* avn = side ? anbv_b : anbv_u;
    unsigned char* Cout = H1f8 + (size_t)side * H1STRIDE8;

    const int wave = tid >> 6, lane = tid & 63;
    const int wr = wave >> 1, wc = wave & 1;
    const int sl = lane & 15, lg = lane >> 4;
    const int K = IN_DIM;

    if (tid < BM) { dotL[tid][0] = 0.f; dotL[tid][1] = 0.f; }

    f32x4 acc[4][4] = {};

    for (int k0 = 0; k0 < K; k0 += BK) {
        __syncthreads();
        #pragma unroll
        for (int p = 0; p < 4; ++p) {
            int q = p * 256 + tid;
            int row = q >> 3;
            int kq = (q & 7) << 3;
            int grow = rowBase + row;
            u16x8 hv = {0, 0, 0, 0, 0, 0, 0, 0};
            if (grow < M) {
                const float* a = Ap + (size_t)grow * K + k0 + kq;
                float4 v0 = *(const float4*)a;
                float4 v1 = *(const float4*)(a + 4);
                hv[0] = f2bf(v0.x); hv[1] = f2bf(v0.y); hv[2] = f2bf(v0.z); hv[3] = f2bf(v0.w);
                hv[4] = f2bf(v1.x); hv[5] = f2bf(v1.y); hv[6] = f2bf(v1.z); hv[7] = f2bf(v1.w);
            }
            *(u16x8*)&AhS[swz(row, kq)] = hv;
        }
        #pragma unroll
        for (int p = 0; p < 4; ++p) {
            int q = p * 256 + tid;
            int n = q >> 3;
            int kq = (q & 7) << 3;
            u16x8 hv = *(const u16x8*)(Bp + (size_t)n * K + k0 + kq);
            *(u16x8*)&BhS[swz(n, kq)] = hv;
        }
        __syncthreads();
        #pragma unroll
        for (int ks = 0; ks < 2; ++ks) {
            int kof = ks * 32 + lg * 8;
            bf16x8 af[4], bf[4];
            #pragma unroll
            for (int f = 0; f < 4; ++f) {
                af[f] = *(const bf16x8*)&AhS[swz(wr * 64 + f * 16 + sl, kof)];
                bf[f] = *(const bf16x8*)&BhS[swz(wc * 64 + f * 16 + sl, kof)];
            }
            #pragma unroll
            for (int fm = 0; fm < 4; ++fm)
                #pragma unroll
                for (int fn = 0; fn < 4; ++fn)
                    acc[fm][fn] = __builtin_amdgcn_mfma_f32_16x16x32_bf16(af[fm], bf[fn], acc[fm][fn], 0, 0, 0);
        }
    }

    // C write (fp8 e4m3, byte stores)
    #pragma unroll
    for (int fm = 0; fm < 4; ++fm)
        #pragma unroll
        for (int r = 0; r < 4; ++r) {
            int row = rowBase + wr * 64 + fm * 16 + lg * 4 + r;
            if (row >= M) continue;
            #pragma unroll
            for (int fn = 0; fn < 4; ++fn) {
                int col = wc * 64 + fn * 16 + sl;
                Cout[(size_t)row * 128 + col] = f2fp8(acc[fm][fn][r]);
            }
        }

    // fused rowdots (full-precision acc)
    float as_[4], an_[4];
    #pragma unroll
    for (int fn = 0; fn < 4; ++fn) {
        int col = wc * 64 + fn * 16 + sl;
        as_[fn] = avs[col];
        an_[fn] = avn[col];
    }
    #pragma unroll
    for (int fm = 0; fm < 4; ++fm)
        #pragma unroll
        for (int r = 0; r < 4; ++r) {
            float p1 = 0.f, p2 = 0.f;
            #pragma unroll
            for (int fn = 0; fn < 4; ++fn) {
                float v = acc[fm][fn][r];
                p1 += v * as_[fn];
                p2 += v * an_[fn];
            }
            #pragma unroll
            for (int o = 1; o <= 8; o <<= 1) {
                p1 += __shfl_xor(p1, o);
                p2 += __shfl_xor(p2, o);
            }
            if (sl == 0) {
                int row_l = wr * 64 + fm * 16 + lg * 4 + r;
                atomicAdd(&dotL[row_l][0], p1);
                atomicAdd(&dotL[row_l][1], p2);
            }
        }
    __syncthreads();
    if (tid < BM) {
        int row = rowBase + tid;
        if (row < M) {
            asf[side * M + row] = dotL[tid][0] * LOGSCALE;
            anb[side * M + row] = dotL[tid][1] * LOGSCALE;
        }
    }
}

// ---------------------------------------------------------------------------
__global__ __launch_bounds__(256)
void bucket_csr(const int* __restrict__ ebuf, const int* __restrict__ bbase,
                int* __restrict__ offs, unsigned short* __restrict__ csr)
{
    __shared__ int lds_e[BCAP];
    __shared__ int cnt[256];
    __shared__ int excl[256];
    __shared__ int cur[256];
    __shared__ int wsum[4];
    int tid = threadIdx.x;
    int b = blockIdx.x;
    int lo = bbase[b], hi = bbase[b + 1];
    int sz = hi - lo;

    cnt[tid] = 0; cur[tid] = 0;
    __syncthreads();
    for (int i = tid; i < sz; i += 256) {
        int v = ebuf[lo + i];
        if (i < BCAP) lds_e[i] = v;
        atomicAdd(&cnt[v >> 16], 1);
    }
    __syncthreads();

    int lane = tid & 63, w = tid >> 6;
    int v = cnt[tid];
    int x = v;
    #pragma unroll
    for (int o = 1; o < 64; o <<= 1) {
        int y = __shfl_up(x, o);
        if (lane >= o) x += y;
    }
    if (lane == 63) wsum[w] = x;
    __syncthreads();
    int wb = 0;
    for (int i = 0; i < w; ++i) wb += wsum[i];
    int ex = wb + x - v;
    excl[tid] = ex;
    int vd = b * 256 + tid;
    if (vd < VN4) offs[vd] = lo + ex;
    __syncthreads();

    for (int i = tid; i < sz; i += 256) {
        int e = (i < BCAP) ? lds_e[i] : ebuf[lo + i];
        int dl = e >> 16;
        int p = excl[dl] + atomicAdd(&cur[dl], 1);
        csr[lo + p] = (unsigned short)(e & 0xFFFF);
    }
}

// ---------------------------------------------------------------------------
// GAT aggregation: fp8 H1 gather, deferred normalization, 16-lane groups,
// 2-deep pipeline, f32 decode via cvt_pk_f32_fp8.
// ---------------------------------------------------------------------------
__global__ __launch_bounds__(256)
void gat_gather(const unsigned char* __restrict__ H1f8, const float* __restrict__ asf,
                const float* __restrict__ anb,
                const int* __restrict__ offs, const unsigned short* __restrict__ csr,
                const float* __restrict__ omu, const float* __restrict__ omb,
                unsigned short* __restrict__ H2h, int n)
{
    int side = blockIdx.y;
    int lane = threadIdx.x & 63, wid = threadIdx.x >> 6;
    int d = blockIdx.x * 4 + wid;
    if (d >= n) return;
    const unsigned char* Hbase = H1f8 + (size_t)side * H1STRIDE8;
    const int* offside = offs + side * 2 * N_NODES;
    const float* om_p = side ? omb : omu;
    float ad = asf[side * n + d];
    const float* anb_s = anb + side * n;
    int sub = lane >> 4, sl = lane & 15;
    const unsigned char* Hp = Hbase + (sl << 3);
    float fin[8] = {};

    #pragma unroll
    for (int g = 0; g < NGRAPH; ++g) {
        int beg = offside[g * n + d], end = offside[g * n + d + 1];
        float om = om_p[g];
        float un[8] = {};
        float ss = 0.f;

        int e = beg + sub;
        for (; e + 4 < end; e += 8) {
            int s0 = csr[e], s1 = csr[e + 4];
            float a0 = anb_s[s0], a1 = anb_s[s1];
            u32x2 b0 = *(const u32x2*)(Hp + (size_t)s0 * 128);
            u32x2 b1 = *(const u32x2*)(Hp + (size_t)s1 * 128);
            float sc0 = ad + a0; sc0 = fmaxf(sc0, 0.2f * sc0);
            float sc1 = ad + a1; sc1 = fmaxf(sc1, 0.2f * sc1);
            float w0 = EXPW(sc0), w1 = EXPW(sc1);
            ss += w0 + w1;
            {
                f32x2 q0 = __builtin_amdgcn_cvt_pk_f32_fp8(b0[0], false);
                f32x2 q1 = __builtin_amdgcn_cvt_pk_f32_fp8(b0[0], true);
                f32x2 q2 = __builtin_amdgcn_cvt_pk_f32_fp8(b0[1], false);
                f32x2 q3 = __builtin_amdgcn_cvt_pk_f32_fp8(b0[1], true);
                un[0] += w0 * q0[0]; un[1] += w0 * q0[1];
                un[2] += w0 * q1[0]; un[3] += w0 * q1[1];
                un[4] += w0 * q2[0]; un[5] += w0 * q2[1];
                un[6] += w0 * q3[0]; un[7] += w0 * q3[1];
            }
            {
                f32x2 q0 = __builtin_amdgcn_cvt_pk_f32_fp8(b1[0], false);
                f32x2 q1 = __builtin_amdgcn_cvt_pk_f32_fp8(b1[0], true);
                f32x2 q2 = __builtin_amdgcn_cvt_pk_f32_fp8(b1[1], false);
                f32x2 q3 = __builtin_amdgcn_cvt_pk_f32_fp8(b1[1], true);
                un[0] += w1 * q0[0]; un[1] += w1 * q0[1];
                un[2] += w1 * q1[0]; un[3] += w1 * q1[1];
                un[4] += w1 * q2[0]; un[5] += w1 * q2[1];
                un[6] += w1 * q3[0]; un[7] += w1 * q3[1];
            }
        }
        if (e < end) {
            int s0 = csr[e];
            float a0 = anb_s[s0];
            u32x2 b0 = *(const u32x2*)(Hp + (size_t)s0 * 128);
            float sc0 = ad + a0; sc0 = fmaxf(sc0, 0.2f * sc0);
            float w0 = EXPW(sc0);
            ss += w0;
            f32x2 q0 = __builtin_amdgcn_cvt_pk_f32_fp8(b0[0], false);
            f32x2 q1 = __builtin_amdgcn_cvt_pk_f32_fp8(b0[0], true);
            f32x2 q2 = __builtin_amdgcn_cvt_pk_f32_fp8(b0[1], false);
            f32x2 q3 = __builtin_amdgcn_cvt_pk_f32_fp8(b0[1], true);
            un[0] += w0 * q0[0]; un[1] += w0 * q0[1];
            un[2] += w0 * q1[0]; un[3] += w0 * q1[1];
            un[4] += w0 * q2[0]; un[5] += w0 * q2[1];
            un[6] += w0 * q3[0]; un[7] += w0 * q3[1];
        }

        // cross-group sum of exp (groups hold disjoint edge subsets)
        ss += __shfl_xor(ss, 32);
        ss += __shfl_xor(ss, 16);
        float wsc = om / (ss + 1e-16f);
        #pragma unroll
        for (int j = 0; j < 8; ++j) fin[j] += wsc * un[j];
    }

    #pragma unroll
    for (int j = 0; j < 8; ++j) {
        fin[j] += __shfl_xor(fin[j], 32);
        fin[j] += __shfl_xor(fin[j], 16);
    }
    if (sub == 0) {
        f16x8 o;
        #pragma unroll
        for (int j = 0; j < 8; ++j) o[j] = (_Float16)fin[j];
        *(f16x8*)(H2h + (size_t)side * HSTRIDE + (size_t)d * LATENT + sl * 8) = o;
    }
}

// ---------------------------------------------------------------------------
// Fused GEMM2+GEMM3: H3 = elu(H2@W2a + S@W2s + b2) in LDS (bf16), then
// OUT = elu(H3@W3) + H4. Pass0 f16 MFMA (H2/W2a f16), pass1 bf16.
// ---------------------------------------------------------------------------
__global__ __launch_bounds__(256)
void gemm_fused23(const unsigned short* __restrict__ H2h,
                  const float* __restrict__ Su, const float* __restrict__ Sb,
                  const unsigned short* __restrict__ wspb,
                  const float* __restrict__ b2u, const float* __restrict__ b2b,
                  const float* __restrict__ H4u, const float* __restrict__ H4b,
                  float* __restrict__ Uo, float* __restrict__ Bo, int M)
{
    __shared__ unsigned short sm[BM * BK * 2];   // AhS/BhS; H3S overlays (32KB)
    __shared__ unsigned short W3S[64 * 128];     // 16KB
    unsigned short* AhS = sm;
    unsigned short* BhS = sm + BM * BK;

    const int side = blockIdx.z;
    const unsigned short* Bside = wspb + (size_t)side * WSP_SIDE;
    const float* bias = side ? b2b : b2u;
    const float* H4 = side ? H4b : H4u;
    float* Cout = side ? Bo : Uo;

    const int tid = threadIdx.x;
    const int rowBase = blockIdx.x * BM;
    const int wave = tid >> 6, lane = tid & 63;
    const int wr = wave >> 1, wc = wave & 1;
    const int sl = lane & 15, lg = lane >> 4;

    // preload W3 [64][128] bf16 k-major (swizzled)
    {
        const unsigned short* w3 = Bside + 81920;
        #pragma unroll
        for (int p = 0; p < 4; ++p) {
            int i = p * 256 + tid;
            int n = i >> 4;
            int kq = (i & 15) << 3;
            u16x8 v = *(const u16x8*)(w3 + (size_t)n * 128 + kq);
            *(u16x8*)&W3S[swz2(n, kq)] = v;
        }
    }

    f32x4 acc[4][4] = {};

    // ---- pass 0: A = H2 (f16), B = W2a (f16), K = 128
    {
        const unsigned short* Ap = H2h + (size_t)side * HSTRIDE;
        const unsigned short* Bp = Bside + 32768;
        const int K = LATENT;
        for (int k0 = 0; k0 < K; k0 += BK) {
            __syncthreads();
            #pragma unroll
            for (int p = 0; p < 4; ++p) {
                int q = p * 256 + tid;
                int row = q >> 3;
                int kq = (q & 7) << 3;
                int grow = rowBase + row;
                u16x8 hv = {0, 0, 0, 0, 0, 0, 0, 0};
                if (grow < M)
                    hv = *(const u16x8*)(Ap + (size_t)grow * K + k0 + kq);
                *(u16x8*)&AhS[swz(row, kq)] = hv;
            }
            #pragma unroll
            for (int p = 0; p < 4; ++p) {
                int q = p * 256 + tid;
                int n = q >> 3;
                int kq = (q & 7) << 3;
                u16x8 hv = *(const u16x8*)(Bp + (size_t)n * K + k0 + kq);
                *(u16x8*)&BhS[swz(n, kq)] = hv;
            }
            __syncthreads();
            #pragma unroll
            for (int ks = 0; ks < 2; ++ks) {
                int kof = ks * 32 + lg * 8;
                f16x8 af[4], bf[4];
                #pragma unroll
                for (int f = 0; f < 4; ++f) {
                    af[f] = *(const f16x8*)&AhS[swz(wr * 64 + f * 16 + sl, kof)];
                    bf[f] = *(const f16x8*)&BhS[swz(wc * 64 + f * 16 + sl, kof)];
                }
                #pragma unroll
                for (int fm = 0; fm < 4; ++fm)
                    #pragma unroll
                    for (int fn = 0; fn < 4; ++fn)
                        acc[fm][fn] = __builtin_amdgcn_mfma_f32_16x16x32_f16(af[fm], bf[fn], acc[fm][fn], 0, 0, 0);
            }
        }
    }

    // ---- pass 1: A = S (f32->bf16), B = W2s (bf16), K = 256
    {
        const float* Ap = side ? Sb : Su;
        const unsigned short* Bp = Bside + 49152;
        const int K = IN_DIM;
        for (int k0 = 0; k0 < K; k0 += BK) {
            __syncthreads();
            #pragma unroll
            for (int p = 0; p < 4; ++p) {
                int q = p * 256 + tid;
                int row = q >> 3;
                int kq = (q & 7) << 3;
                int grow = rowBase + row;
                u16x8 hv = {0, 0, 0, 0, 0, 0, 0, 0};
                if (grow < M) {
                    const float* a = Ap + (size_t)grow * K + k0 + kq;
                    float4 v0 = *(const float4*)a;
                    float4 v1 = *(const float4*)(a + 4);
                    hv[0] = f2bf(v0.x); hv[1] = f2bf(v0.y); hv[2] = f2bf(v0.z); hv[3] = f2bf(v0.w);
                    hv[4] = f2bf(v1.x); hv[5] = f2bf(v1.y); hv[6] = f2bf(v1.z); hv[7] = f2bf(v1.w);
                }
                *(u16x8*)&AhS[swz(row, kq)] = hv;
            }
            #pragma unroll
            for (int p = 0; p < 4; ++p) {
                int q = p * 256 + tid;
                int n = q >> 3;
                int kq = (q & 7) << 3;
                u16x8 hv = *(const u16x8*)(Bp + (size_t)n * K + k0 + kq);
                *(u16x8*)&BhS[swz(n, kq)] = hv;
            }
            __syncthreads();
            #pragma unroll
            for (int ks = 0; ks < 2; ++ks) {
                int kof = ks * 32 + lg * 8;
                bf16x8 af[4], bf[4];
                #pragma unroll
                for (int f = 0; f < 4; ++f) {
                    af[f] = *(const bf16x8*)&AhS[swz(wr * 64 + f * 16 + sl, kof)];
                    bf[f] = *(const bf16x8*)&BhS[swz(wc * 64 + f * 16 + sl, kof)];
                }
                #pragma unroll
                for (int fm = 0; fm < 4; ++fm)
                    #pragma unroll
                    for (int fn = 0; fn < 4; ++fn)
                        acc[fm][fn] = __builtin_amdgcn_mfma_f32_16x16x32_bf16(af[fm], bf[fn], acc[fm][fn], 0, 0, 0);
            }
        }
    }

    __syncthreads();   // main-loop LDS reads done; reuse sm as H3S
    unsigned short* H3S = sm;   // [128][128] bf16, swz2

    // epilogue 1: H3 = elu(acc + b2) -> LDS
    #pragma unroll
    for (int fm = 0; fm < 4; ++fm)
        #pragma unroll
        for (int r = 0; r < 4; ++r) {
            int row_l = wr * 64 + fm * 16 + lg * 4 + r;
            #pragma unroll
            for (int fn = 0; fn < 4; ++fn) {
                int col = wc * 64 + fn * 16 + sl;
                float v = acc[fm][fn][r] + bias[col];
                v = v > 0.f ? v : (__expf(v) - 1.f);
                H3S[swz2(row_l, col)] = f2bf(v);
            }
        }
    __syncthreads();

    // matmul2: OUT[128][64] = H3 @ W3, K=128 (bf16)
    f32x4 acc2[4][2] = {};
    #pragma unroll
    for (int ks = 0; ks < 4; ++ks) {
        int kof = ks * 32 + lg * 8;
        bf16x8 a2[4], b2f[2];
        #pragma unroll
        for (int f = 0; f < 4; ++f)
            a2[f] = *(const bf16x8*)&H3S[swz2(wr * 64 + f * 16 + sl, kof)];
        #pragma unroll
        for (int f = 0; f < 2; ++f)
            b2f[f] = *(const bf16x8*)&W3S[swz2(wc * 32 + f * 16 + sl, kof)];
        #pragma unroll
        for (int fm = 0; fm < 4; ++fm)
            #pragma unroll
            for (int fn = 0; fn < 2; ++fn)
                acc2[fm][fn] = __builtin_amdgcn_mfma_f32_16x16x32_bf16(a2[fm], b2f[fn], acc2[fm][fn], 0, 0, 0);
    }

    // epilogue 2: OUT = elu(acc2) + H4
    #pragma unroll
    for (int fm = 0; fm < 4; ++fm)
        #pragma unroll
        for (int r = 0; r < 4; ++r) {
            int row = rowBase + wr * 64 + fm * 16 + lg * 4 + r;
            if (row >= M) continue;
            #pragma unroll
            for (int fn = 0; fn < 2; ++fn) {
                int col = wc * 32 + fn * 16 + sl;
                float v = acc2[fm][fn][r];
                v = v > 0.f ? v : (__expf(v) - 1.f);
                v += H4[(size_t)row * FINALD + col];
                Cout[(size_t)row * FINALD + col] = v;
            }
        }
}

// ---------------------------------------------------------------------------
__global__ __launch_bounds__(256)
void predict(const int* __restrict__ uid, const int* __restrict__ iid,
             const float* __restrict__ U, const float* __restrict__ B,
             const float* __restrict__ bu, const float* __restrict__ bb,
             const float* __restrict__ bx, float* __restrict__ out, int batch)
{
    int lane = threadIdx.x & 63, wid = threadIdx.x >> 6;
    int b = blockIdx.x * 4 + wid;
    if (b >= batch) return;
    int u = uid[b], it = iid[b];
    float p = U[(size_t)u * FINALD + lane] * B[(size_t)it * FINALD + lane];
    #pragma unroll
    for (int o = 32; o; o >>= 1) p += __shfl_xor(p, o);
    if (lane == 0) {
        float raw = p + bu[u] + bb[it] + bx[0];
        out[b] = 4.f * (1.f / (1.f + __expf(-raw))) + 1.f;
    }
}

// ---------------------------------------------------------------------------
extern "C" void kernel_launch(void* const* d_in, const int* in_sizes, int n_in,
                              void* d_out, int out_size, void* d_ws, size_t ws_size,
                              hipStream_t stream)
{
    const int N = N_NODES;

    float* ws = (float*)d_ws;
    unsigned char* H1f8 = (unsigned char*)ws;            // 2 sides fp8 (12.8 MB)
    unsigned short* H2h = (unsigned short*)(ws + 6400000);
    float* U_all = ws + 12800000;
    float* B_all = ws + 16000000;
    float* asf   = ws + 19200000;                        // [2][N]
    float* anb   = asf + 2 * N;                          // [2][N]
    int*   offs  = (int*)(anb + 2 * N);                  // VN4+1
    int*   bbase = offs + VN4 + 1;                       // NBU+1
    unsigned short* csr = (unsigned short*)(bbase + NBU + 1);  // E4 ushorts
    unsigned short* wsp = (unsigned short*)(((uintptr_t)(csr + E4) + 15) & ~(uintptr_t)15);
    int*   ebuf  = (int*)H2h;                            // E4 ints (dead before gather)
    int*   pcnt  = (int*)U_all;                          // NBU*NPB
    int*   pbase = pcnt + NBU * NPB;                     // NBU*NPB
    int*   btotg = pbase + NBU * NPB;                    // NBU

    const int* eU = (const int*)d_in[4];
    const int* eB = (const int*)d_in[5];
    const float* Su = (const float*)d_in[2];
    const float* Sb = (const float*)d_in[3];

    // FAT1: edge histogram || weight prep
    fat_count_prep<<<NPB + PREPB, 256, 0, stream>>>(
        eU, eB, pcnt,
        (const float*)d_in[6],  (const float*)d_in[14], (const float*)d_in[15], (const float*)d_in[20],
        (const float*)d_in[10], (const float*)d_in[17], (const float*)d_in[18], (const float*)d_in[21],
        wsp);

    // hierarchical scan (split; parallel phase A + tiny phase B)
    part_scanA<<<NBU, 64, 0, stream>>>(pcnt, pbase, btotg);
    part_scanB<<<1, 1024, 0, stream>>>(btotg, bbase, offs);

    // FAT2: edge partition fill || H1 GEMM + rowdots
    fat_fill_gemm1<<<NPB + 782, 256, 0, stream>>>(
        eU, eB, pbase, bbase, ebuf,
        Su, Sb, wsp,
        (const float*)d_in[7], (const float*)d_in[8],
        (const float*)d_in[11], (const float*)d_in[12],
        H1f8, asf, anb, N);

    bucket_csr<<<NBU, 256, 0, stream>>>(ebuf, bbase, offs, csr);

    gat_gather<<<dim3(N / 4, 2), 256, 0, stream>>>(
        H1f8, asf, anb, offs, csr,
        (const float*)d_in[9], (const float*)d_in[13], H2h, N);

    gemm_fused23<<<dim3(391, 1, 2), 256, 0, stream>>>(
        H2h, Su, Sb, wsp,
        (const float*)d_in[16], (const float*)d_in[19],
        (const float*)d_in[22], (const float*)d_in[23],
        U_all, B_all, N);

    predict<<<BATCHSZ / 4, 256, 0, stream>>>(
        (const int*)d_in[0], (const int*)d_in[1], U_all, B_all,
        (const float*)d_in[24], (const float*)d_in[25], (const float*)d_in[26],
        (float*)d_out, BATCHSZ);
}